// Round 3
// baseline (223.711 us; speedup 1.0000x reference)
//
#include <hip/hip_runtime.h>

// LIF/IF activation, T=4, v_th=1, subtractive reset (fwd only).
// out = (sum_{t=1..4} H(v_t - 1)) / 4 * safe_scale, with
//   c = relu(x) / safe_scale;  v <- v + c;  s = H(v-1);  v <- v - s.
// fp32 step-by-step arithmetic matches the numpy reference bit-for-bit
// (IEEE division kept — reciprocal-multiply can flip spikes at threshold
// crossings, each flip = 0.375 absmax vs threshold 0.03).
//
// Memory-bound streaming kernel: 128 MiB read + 128 MiB write.
// Each thread handles 4 vec4s (64 B), block-strided for coalescing.
// Nontemporal loads/stores (read-once/write-once data). Uses a native clang
// ext_vector_type float4 — __builtin_nontemporal_* rejects HIP_vector_type.

typedef float vfloat4 __attribute__((ext_vector_type(4)));

#define VPT 4  // vec4s per thread

__device__ __forceinline__ float lif_elem(float x, float safe_scale) {
    float c = fmaxf(x, 0.0f) / safe_scale;   // IEEE fp32 division (no fast-math)
    float v = 0.0f;
    float cnt = 0.0f;
#pragma unroll
    for (int t = 0; t < 4; ++t) {
        v += c;
        float s = ((v - 1.0f) >= 0.0f) ? 1.0f : 0.0f;
        v -= s;
        cnt += s;
    }
    return (cnt * 0.25f) * safe_scale;
}

__global__ __launch_bounds__(256) void lif_kernel(const vfloat4* __restrict__ x,
                                                  const float* __restrict__ scale_p,
                                                  vfloat4* __restrict__ out,
                                                  int n4) {
    const float safe_scale = fmaxf(scale_p[0], 1e-12f);  // scalar broadcast
    int base = blockIdx.x * (256 * VPT) + threadIdx.x;
#pragma unroll
    for (int k = 0; k < VPT; ++k) {
        int idx = base + k * 256;
        if (idx < n4) {
            vfloat4 xv = __builtin_nontemporal_load(&x[idx]);
            vfloat4 ov;
            ov.x = lif_elem(xv.x, safe_scale);
            ov.y = lif_elem(xv.y, safe_scale);
            ov.z = lif_elem(xv.z, safe_scale);
            ov.w = lif_elem(xv.w, safe_scale);
            __builtin_nontemporal_store(ov, &out[idx]);
        }
    }
}

// Scalar tail for n % 4 != 0 (not hit for 4096x8192; kept for safety).
__global__ void lif_tail_kernel(const float* __restrict__ x,
                                const float* __restrict__ scale_p,
                                float* __restrict__ out,
                                int start, int n) {
    int idx = start + blockIdx.x * blockDim.x + threadIdx.x;
    if (idx >= n) return;
    float safe_scale = fmaxf(scale_p[0], 1e-12f);
    out[idx] = lif_elem(x[idx], safe_scale);
}

extern "C" void kernel_launch(void* const* d_in, const int* in_sizes, int n_in,
                              void* d_out, int out_size, void* d_ws, size_t ws_size,
                              hipStream_t stream) {
    const float* x = (const float*)d_in[0];
    const float* scale = (const float*)d_in[1];
    float* out = (float*)d_out;
    int n = in_sizes[0];
    int n4 = n >> 2;

    if (n4 > 0) {
        int per_block = 256 * VPT;
        int blocks = (n4 + per_block - 1) / per_block;
        lif_kernel<<<blocks, 256, 0, stream>>>((const vfloat4*)x, scale,
                                               (vfloat4*)out, n4);
    }
    int tail_start = n4 << 2;
    int tail = n - tail_start;
    if (tail > 0) {
        lif_tail_kernel<<<1, 64, 0, stream>>>(x, scale, out, tail_start, n);
    }
}